// Round 9
// baseline (210.572 us; speedup 1.0000x reference)
//
#include <hip/hip_runtime.h>

#define HID   1024
#define SLEN  2048
#define NHEAD 16
#define HDIM  64
#define SC2L  0.18033688f   // (1/sqrt(64)) * log2(e)

typedef unsigned short u16;
typedef unsigned int u32;
typedef _Float16 f16;
using bf16x8 = __attribute__((ext_vector_type(8))) short;
using h16x2  = __attribute__((ext_vector_type(2))) __fp16;
using h16x4  = __attribute__((ext_vector_type(4))) __fp16;
using f16x4  = __attribute__((ext_vector_type(4))) f16;
using f32x4  = __attribute__((ext_vector_type(4))) float;

typedef __attribute__((address_space(1))) void gvoid;
typedef __attribute__((address_space(3))) void lvoid;

__device__ __forceinline__ u16 f2bf(float f) {
  union { float f; unsigned u; } v; v.f = f;
  unsigned u = v.u;
  return (u16)((u + 0x7fffu + ((u >> 16) & 1u)) >> 16);
}

__device__ __forceinline__ void async_ld16(const u16* g, u16* l) {
  __builtin_amdgcn_global_load_lds((gvoid*)g, (lvoid*)l, 16, 0, 0);
}

// Partial-drain barriers: keep the newest N async loads in flight across the
// barrier (AITER-style "vmcnt never 0"). Per-wave FIFO retirement + barrier
// guarantees every wave's OLDER group has landed in LDS for all waves.
__device__ __forceinline__ void barrier_keep4() {
  asm volatile("s_waitcnt vmcnt(4)\ns_barrier" ::: "memory");
}
__device__ __forceinline__ void barrier_keep0() {
  asm volatile("s_waitcnt vmcnt(0)\ns_barrier" ::: "memory");
}

// -------- prep: z<4 -> transpose+cast weight z; z==4 -> cast X fp32->bf16 --------
__global__ __launch_bounds__(256) void prep_kernel(const float* __restrict__ x,
                                                   const float* __restrict__ wq,
                                                   const float* __restrict__ wk,
                                                   const float* __restrict__ wv,
                                                   const float* __restrict__ wo,
                                                   u16* __restrict__ xb,
                                                   u16* __restrict__ wt) {
  const int tid = threadIdx.x;
  if (blockIdx.z == 4) {
    const int bid = blockIdx.y * 32 + blockIdx.x;
#pragma unroll
    for (int it = 0; it < 4; ++it) {
      const int i = bid * 1024 + it * 256 + tid;
      float4 v = ((const float4*)x)[i];
      ushort4 o;
      o.x = f2bf(v.x); o.y = f2bf(v.y); o.z = f2bf(v.z); o.w = f2bf(v.w);
      ((ushort4*)xb)[i] = o;
    }
    return;
  }
  const float* src = (blockIdx.z == 0) ? wq : (blockIdx.z == 1) ? wk
                   : (blockIdx.z == 2) ? wv : wo;
  u16* dst = wt + (size_t)blockIdx.z * (HID * HID);
  __shared__ float tile[32][33];
  const int n0 = blockIdx.x * 32, k0 = blockIdx.y * 32;
  const int xx = tid & 31, yy = tid >> 5;
  for (int i = yy; i < 32; i += 8)
    tile[i][xx] = src[(size_t)(k0 + i) * HID + n0 + xx];
  __syncthreads();
  for (int i = yy; i < 32; i += 8)
    dst[(size_t)(n0 + i) * HID + k0 + xx] = f2bf(tile[xx][i]);
}

// ------------- fused QKV GEMM -------------
// Q,K written row-major bf16. V written TRANSPOSED f16 to VT[b,h,d,s] via an
// LDS-transpose epilogue (xor-swizzled chunks), so flash needs no V conversion.
__global__ __launch_bounds__(256) void gemm_qkv_kernel(const u16* __restrict__ A,
                                                       const u16* __restrict__ Bt,
                                                       const float* __restrict__ bq,
                                                       const float* __restrict__ bk,
                                                       const float* __restrict__ bv,
                                                       u16* __restrict__ Qb,
                                                       u16* __restrict__ Kb,
                                                       u16* __restrict__ VTf) {
  __shared__ u16 smem[8192];                 // sA | sB, contiguous 16 KB
  u16* sA = smem;
  u16* sB = smem + 4096;
  const int tid  = threadIdx.x;
  const int wave = tid >> 6, lane = tid & 63;
  const int quad = lane >> 4, l16 = lane & 15;
  const int n0g = blockIdx.x * 128;
  const int region = blockIdx.x >> 3;        // 0=Q 1=K 2=V
  const int colbase = (blockIdx.x & 7) * 128;
  const int m0 = blockIdx.y * 128;
  const int wm = (wave & 1) * 64, wn = (wave >> 1) * 64;

  f32x4 acc[4][4] = {};
  const int srow = lane >> 2;
  const int scol = (lane & 3) * 8;

  for (int kt = 0; kt < HID; kt += 32) {
    __syncthreads();
    for (int c = wave; c < 8; c += 4) {
      async_ld16(A  + (size_t)(m0  + c * 16 + srow) * HID + kt + scol, &sA[c * 512]);
      async_ld16(Bt + (size_t)(n0g + c * 16 + srow) * HID + kt + scol, &sB[c * 512]);
    }
    __syncthreads();

    bf16x8 af[4], bfr[4];
#pragma unroll
    for (int t = 0; t < 4; ++t) {
      af[t]  = *(const bf16x8*)&sA[(wm + t * 16 + l16) * 32 + quad * 8];
      bfr[t] = *(const bf16x8*)&sB[(wn + t * 16 + l16) * 32 + quad * 8];
    }
#pragma unroll
    for (int mt = 0; mt < 4; ++mt)
#pragma unroll
      for (int nt = 0; nt < 4; ++nt)
        acc[mt][nt] = __builtin_amdgcn_mfma_f32_16x16x32_bf16(af[mt], bfr[nt],
                                                              acc[mt][nt], 0, 0, 0);
  }

  const float* bias = (region == 0) ? bq : (region == 1) ? bk : bv;
  float bvv[4];
#pragma unroll
  for (int nt = 0; nt < 4; ++nt) bvv[nt] = bias[colbase + wn + nt * 16 + l16];

  if (region == 2) {
    // --- transposed f16 epilogue: VT[(b*16+h)*64+d][s], two 64-col halves ---
    const int bb = m0 >> 11;            // batch
    const int m0loc = m0 & 2047;        // s offset within batch
    const int h0 = colbase >> 6;        // first head in this 128-col span
    u16* T = smem;                      // [64 d][128 s] u16, chunk-swizzled
#pragma unroll
    for (int h2 = 0; h2 < 2; ++h2) {
      __syncthreads();                  // prior readers of smem done
      if ((wave >> 1) == h2) {          // waves owning this 64-col half
#pragma unroll
        for (int mt = 0; mt < 4; ++mt)
#pragma unroll
          for (int nt = 0; nt < 4; ++nt)
#pragma unroll
            for (int r = 0; r < 4; ++r) {
              const int sl = (wave & 1) * 64 + mt * 16 + quad * 4 + r;  // 0..127
              const int dl = nt * 16 + l16;                             // 0..63
              union { f16 h; u16 u; } cv;
              cv.h = (f16)(acc[mt][nt][r] + bvv[nt]);
              T[dl * 128 + (((sl >> 3) ^ l16) * 8) + (sl & 7)] = cv.u;
            }
      }
      __syncthreads();
      const int d = tid >> 2, sg = (tid & 3) * 4;
      u16* drow = VTf + (size_t)((bb * NHEAD + h0 + h2) * HDIM + d) * SLEN + m0loc;
#pragma unroll
      for (int cc = 0; cc < 4; ++cc) {
        const int cl = sg + cc;
        const int ph = cl ^ (d & 15);
        *(bf16x8*)(drow + cl * 8) = *(const bf16x8*)&T[d * 128 + ph * 8];
      }
    }
    return;
  }

  u16* C = (region == 0) ? Qb : Kb;
#pragma unroll
  for (int mt = 0; mt < 4; ++mt)
#pragma unroll
    for (int r = 0; r < 4; ++r) {
      const int row = m0 + wm + mt * 16 + quad * 4 + r;
#pragma unroll
      for (int nt = 0; nt < 4; ++nt) {
        const int col = colbase + wn + nt * 16 + l16;
        C[(size_t)row * HID + col] = f2bf(acc[mt][nt][r] + bvv[nt]);
      }
    }
}

// ------------- O-proj GEMM: out[4096][1024] = A @ Wt^T + b (fp32 out) -------------
__global__ __launch_bounds__(256) void gemm_o_kernel(const u16* __restrict__ A,
                                                     const u16* __restrict__ Bt,
                                                     const float* __restrict__ bias,
                                                     float* __restrict__ Cf) {
  __shared__ u16 sA[64 * 32];
  __shared__ u16 sB[128 * 32];
  const int tid  = threadIdx.x;
  const int wave = tid >> 6, lane = tid & 63;
  const int quad = lane >> 4, l16 = lane & 15;
  const int n0 = blockIdx.x * 128;
  const int m0 = blockIdx.y * 64;
  const int wn = wave * 32;

  f32x4 acc[4][2] = {};
  const int srow = lane >> 2;
  const int scol = (lane & 3) * 8;

  for (int kt = 0; kt < HID; kt += 32) {
    __syncthreads();
    for (int c = wave; c < 12; c += 4) {
      if (c < 4) async_ld16(A  + (size_t)(m0 + c * 16 + srow) * HID + kt + scol, &sA[c * 512]);
      else       async_ld16(Bt + (size_t)(n0 + (c - 4) * 16 + srow) * HID + kt + scol,
                            &sB[(c - 4) * 512]);
    }
    __syncthreads();

    bf16x8 af[4], bfr[2];
#pragma unroll
    for (int t = 0; t < 4; ++t)
      af[t] = *(const bf16x8*)&sA[(t * 16 + l16) * 32 + quad * 8];
#pragma unroll
    for (int t = 0; t < 2; ++t)
      bfr[t] = *(const bf16x8*)&sB[(wn + t * 16 + l16) * 32 + quad * 8];
#pragma unroll
    for (int mt = 0; mt < 4; ++mt)
#pragma unroll
      for (int nt = 0; nt < 2; ++nt)
        acc[mt][nt] = __builtin_amdgcn_mfma_f32_16x16x32_bf16(af[mt], bfr[nt],
                                                              acc[mt][nt], 0, 0, 0);
  }

  float bvv[2];
#pragma unroll
  for (int nt = 0; nt < 2; ++nt) bvv[nt] = bias[n0 + wn + nt * 16 + l16];
#pragma unroll
  for (int mt = 0; mt < 4; ++mt)
#pragma unroll
    for (int r = 0; r < 4; ++r) {
      const int row = m0 + mt * 16 + quad * 4 + r;
#pragma unroll
      for (int nt = 0; nt < 2; ++nt)
        Cf[(size_t)row * HID + n0 + wn + nt * 16 + l16] = acc[mt][nt][r] + bvv[nt];
    }
}

// ---------------- causal flash attention, v7 ----------------
// 3-buffer depth-2 async pipeline with partial-drain barriers (vmcnt(4), never 0
// mid-loop): prefetch j+2 stays in flight across the barrier while j+1 lands.
// Mask lives in a 256B LDS bitset (zero VMEM in steady state). 64-k tiles,
// one q-tile per block, grid (32,16,2) swizzled.
__global__ __launch_bounds__(256, 3) void flash_attn_kernel(const u16* __restrict__ Q,
                                                            const u16* __restrict__ K,
                                                            const u16* __restrict__ VT,
                                                            const int* __restrict__ mask,
                                                            u16* __restrict__ O) {
  const int h = blockIdx.y, b = blockIdx.z;
  const int qt = (blockIdx.x + 2 * h + b) & 31;   // bijective per (h,b)
  const int tid  = threadIdx.x;
  const int wave = tid >> 6, lane = tid & 63;
  const int quad = lane >> 4, l16 = lane & 15;
  const int q0 = qt * 64;
  const int jmax = qt + 1;

  __shared__ alignas(16) char smraw[50688];
  // tiles[3] at offsets 0/16K/32K: each = Ks[64k][64d] bf16 (8KB) | Vt[64d][64k] f16 (8KB)
  u16*   mb32 = (u16*)(smraw + 49152);       // 256B mask bitset (u32[64])
  float* lb   = (float*)(smraw + 49664);     // [4][64]
  float* Ob0  = (float*)smraw;               // [64][66] f32 (epilogue alias)
  float* Ob1  = (float*)(smraw + 16896);

  const u16* Kh  = K  + (size_t)b * SLEN * HID + h * HDIM;
  const u16* Vth = VT + (size_t)((b * NHEAD + h) * HDIM) * SLEN;

  // ---- mask -> LDS bitset (once per block) ----
  {
    const int4 m0i = *(const int4*)(mask + b * SLEN + tid * 8);
    const int4 m1i = *(const int4*)(mask + b * SLEN + tid * 8 + 4);
    unsigned byte = (m0i.x ? 1u : 0u) | (m0i.y ? 2u : 0u) | (m0i.z ? 4u : 0u) |
                    (m0i.w ? 8u : 0u) | (m1i.x ? 16u : 0u) | (m1i.y ? 32u : 0u) |
                    (m1i.z ? 64u : 0u) | (m1i.w ? 128u : 0u);
    ((unsigned char*)mb32)[tid] = (unsigned char)byte;
  }

  // Q B-frags: B[d=quad*8+e (+32)][q=nt*16+l16]
  bf16x8 qb[4][2];
#pragma unroll
  for (int nt = 0; nt < 4; ++nt) {
    const u16* qp = Q + (size_t)(b * SLEN + q0 + nt * 16 + l16) * HID + h * HDIM + quad * 8;
    qb[nt][0] = *(const bf16x8*)qp;
    qb[nt][1] = *(const bf16x8*)(qp + 32);
  }
  __syncthreads();   // mask bitset visible

  f32x4 oacc[4][4] = {};                   // k-partial O^T [dt][nt]
  float l_part[4] = {0.f, 0.f, 0.f, 0.f};

  // staging geometry: per wave 2 K asyncs + 2 V asyncs per tile
  const int kr8 = lane >> 3, kc = lane & 7;
  const int gch = kc ^ kr8;                // xor-swizzled 16B chunk

#define STAGE(J, IDX)                                                            \
  {                                                                              \
    u16* Kp = (u16*)smraw + (IDX) * 8192;                                        \
    u16* Vp = Kp + 4096;                                                         \
    const int kb_ = (J) * 64;                                                    \
    async_ld16(Kh + (size_t)(kb_ + wave * 16 + kr8) * HID + gch * 8,             \
               Kp + (wave * 16) * 64);                                           \
    async_ld16(Kh + (size_t)(kb_ + wave * 16 + 8 + kr8) * HID + gch * 8,         \
               Kp + (wave * 16 + 8) * 64);                                       \
    async_ld16(Vth + (size_t)(wave * 16 + kr8) * SLEN + kb_ + gch * 8,           \
               Vp + (wave * 16) * 64);                                           \
    async_ld16(Vth + (size_t)(wave * 16 + 8 + kr8) * SLEN + kb_ + gch * 8,       \
               Vp + (wave * 16 + 8) * 64);                                       \
  }

  STAGE(0, 0);
  if (jmax > 1) { STAGE(1, 1); barrier_keep4(); }
  else          { barrier_keep0(); }

  const int rx = l16 & 7;
  const int ph0 = quad ^ rx;                        // K-frag chunk slots
  const int vslot = (wave * 2 + (quad >> 1)) ^ rx;  // V-frag chunk slot
  const int vsub = vslot * 8 + (quad & 1) * 4;

  for (int j = 0; j < jmax; ++j) {
    u16* KsB = (u16*)smraw + (j % 3) * 8192;
    u16* VtB = KsB + 4096;
    const bool pf = (j + 2 < jmax);
    if (pf) STAGE(j + 2, (j + 2) % 3);

    // mask bits for this wave's k-strip (broadcast LDS read)
    const unsigned mword = ((const u32*)mb32)[j * 2 + (wave >> 1)];
    const unsigned mb4 = (mword >> (((wave & 1) * 16) + quad * 4)) & 0xFu;

    // ---- S^T strip: A = K rows (this wave's 16), B = Q^T ----
    const u16* kp = KsB + (wave * 16 + l16) * 64;
    const bf16x8 ka0 = *(const bf16x8*)(kp + ph0 * 8);
    const bf16x8 ka1 = *(const bf16x8*)(kp + (ph0 ^ 4) * 8);

    float p[4][4];
#pragma unroll
    for (int nt = 0; nt < 4; ++nt) {
      f32x4 z = {0.f, 0.f, 0.f, 0.f};
      z = __builtin_amdgcn_mfma_f32_16x16x32_bf16(ka0, qb[nt][0], z, 0, 0, 0);
      z = __builtin_amdgcn_mfma_f32_16x16x32_bf16(ka1, qb[nt][1], z, 0, 0, 0);
#pragma unroll
      for (int r = 0; r < 4; ++r) {
        float pv = exp2f(z[r] * SC2L);
        pv = (mb4 & (1u << r)) ? pv : 0.f;           // key mask
        p[nt][r] = pv;
      }
    }
    if (j == jmax - 1) {   // causal zeroing on diagonal tile (block-uniform)
#pragma unroll
      for (int nt = 0; nt < 4; ++nt)
#pragma unroll
        for (int r = 0; r < 4; ++r)
          if (wave * 16 + quad * 4 + r > nt * 16 + l16) p[nt][r] = 0.f;
    }

    f16x4 pb[4];
#pragma unroll
    for (int nt = 0; nt < 4; ++nt) {
      l_part[nt] += (p[nt][0] + p[nt][1]) + (p[nt][2] + p[nt][3]);
      const h16x2 lo = __builtin_amdgcn_cvt_pkrtz(p[nt][0], p[nt][1]);
      const h16x2 hi = __builtin_amdgcn_cvt_pkrtz(p[nt][2], p[nt][3]);
      const h16x4 packed = __builtin_shufflevector(lo, hi, 0, 1, 2, 3);
      pb[nt] = __builtin_bit_cast(f16x4, packed);
    }

    // ---- PV: O^T[d][q] += V^T(strip) . P^T(strip), 16x16x16 f16 ----
#pragma unroll
    for (int dt = 0; dt < 4; ++dt) {
      const f16x4 va = *(const f16x4*)(VtB + (dt * 16 + l16) * 64 + vsub);
#pragma unroll
      for (int nt = 0; nt < 4; ++nt)
        oacc[dt][nt] = __builtin_amdgcn_mfma_f32_16x16x16f16(va, pb[nt], oacc[dt][nt], 0, 0, 0);
    }

    if (pf) barrier_keep4();   // j+1 landed; j+2 stays in flight
    else    barrier_keep0();
  }
#undef STAGE

  // ---- epilogue: reduce l over quads; pairwise O^T reduction in LDS ----
#pragma unroll
  for (int nt = 0; nt < 4; ++nt) {
    l_part[nt] += __shfl_xor(l_part[nt], 16);
    l_part[nt] += __shfl_xor(l_part[nt], 32);
  }
  if (quad == 0)
#pragma unroll
    for (int nt = 0; nt < 4; ++nt) lb[wave * 64 + nt * 16 + l16] = l_part[nt];

  if ((wave & 1) == 0) {
    float* ob = (wave == 0) ? Ob0 : Ob1;
#pragma unroll
    for (int dt = 0; dt < 4; ++dt)
#pragma unroll
      for (int nt = 0; nt < 4; ++nt)
#pragma unroll
        for (int r = 0; r < 4; ++r)
          ob[(dt * 16 + quad * 4 + r) * 66 + nt * 16 + l16] = oacc[dt][nt][r];
  }
  __syncthreads();
  if (wave & 1) {
    float* ob = (wave == 1) ? Ob0 : Ob1;
#pragma unroll
    for (int dt = 0; dt < 4; ++dt)
#pragma unroll
      for (int nt = 0; nt < 4; ++nt)
#pragma unroll
        for (int r = 0; r < 4; ++r)
          ob[(dt * 16 + quad * 4 + r) * 66 + nt * 16 + l16] += oacc[dt][nt][r];
  }
  __syncthreads();

  {  // final: thread t -> q = t>>2, 16-d chunk = t&3; normalize + bf16 store
    const int q  = tid >> 2;
    const int dc = tid & 3;
    const float l = lb[q] + lb[64 + q] + lb[128 + q] + lb[192 + q];
    const float inv = 1.f / l;
    u16 ob[16];
#pragma unroll
    for (int e = 0; e < 16; ++e) {
      const int d = dc * 16 + e;
      ob[e] = f2bf((Ob0[d * 66 + q] + Ob1[d * 66 + q]) * inv);
    }
    u16* op = O + (size_t)(b * SLEN + q0 + q) * HID + h * HDIM + dc * 16;
    *(bf16x8*)op       = *(bf16x8*)&ob[0];
    *(bf16x8*)(op + 8) = *(bf16x8*)&ob[8];
  }
}

// ---------------- launcher ----------------
extern "C" void kernel_launch(void* const* d_in, const int* in_sizes, int n_in,
                              void* d_out, int out_size, void* d_ws, size_t ws_size,
                              hipStream_t stream) {
  const float* x    = (const float*)d_in[0];
  const int*   mask = (const int*)d_in[1];
  const float* wq   = (const float*)d_in[2];
  const float* bq   = (const float*)d_in[3];
  const float* wk   = (const float*)d_in[4];
  const float* bk   = (const float*)d_in[5];
  const float* wv   = (const float*)d_in[6];
  const float* bv   = (const float*)d_in[7];
  const float* wo   = (const float*)d_in[8];
  const float* bo   = (const float*)d_in[9];
  float* out = (float*)d_out;

  char* ws = (char*)d_ws;
  u16* XBF = (u16*)(ws);                      // 8 MB (dead after QKV GEMM)
  u16* WT  = (u16*)(ws + (8u  << 20));        // 4x2 MB transposed bf16 weights
  u16* QBF = (u16*)(ws + (16u << 20));        // 8 MB
  u16* KBF = (u16*)(ws + (24u << 20));        // 8 MB
  u16* VTF = (u16*)(ws + (32u << 20));        // 8 MB f16 V^T [b,h,d,s]
  u16* ATT = (u16*)(ws);                      // 8 MB, reuses XBF slot

  prep_kernel<<<dim3(32, 32, 5), 256, 0, stream>>>(x, wq, wk, wv, wo, XBF, WT);
  gemm_qkv_kernel<<<dim3(24, 32), 256, 0, stream>>>(XBF, WT, bq, bk, bv, QBF, KBF, VTF);
  flash_attn_kernel<<<dim3(32, NHEAD, 2), 256, 0, stream>>>(QBF, KBF, VTF, mask, ATT);
  gemm_o_kernel<<<dim3(8, 64), 256, 0, stream>>>(ATT, WT + (3u << 20), bo, out);
}

// Round 10
// 209.556 us; speedup vs baseline: 1.0048x; 1.0048x over previous
//
#include <hip/hip_runtime.h>

#define HID   1024
#define SLEN  2048
#define NHEAD 16
#define HDIM  64
#define SC2L  0.18033688f   // (1/sqrt(64)) * log2(e)

typedef unsigned short u16;
typedef unsigned int u32;
typedef _Float16 f16;
using bf16x8 = __attribute__((ext_vector_type(8))) short;
using h16x2  = __attribute__((ext_vector_type(2))) __fp16;
using h16x4  = __attribute__((ext_vector_type(4))) __fp16;
using f16x4  = __attribute__((ext_vector_type(4))) f16;
using f32x4  = __attribute__((ext_vector_type(4))) float;

typedef __attribute__((address_space(1))) void gvoid;
typedef __attribute__((address_space(3))) void lvoid;

__device__ __forceinline__ u16 f2bf(float f) {
  union { float f; unsigned u; } v; v.f = f;
  unsigned u = v.u;
  return (u16)((u + 0x7fffu + ((u >> 16) & 1u)) >> 16);
}

__device__ __forceinline__ void async_ld16(const u16* g, u16* l) {
  __builtin_amdgcn_global_load_lds((gvoid*)g, (lvoid*)l, 16, 0, 0);
}

// -------- prep: z<4 -> transpose+cast weight z; z==4 -> cast X fp32->bf16 --------
__global__ __launch_bounds__(256) void prep_kernel(const float* __restrict__ x,
                                                   const float* __restrict__ wq,
                                                   const float* __restrict__ wk,
                                                   const float* __restrict__ wv,
                                                   const float* __restrict__ wo,
                                                   u16* __restrict__ xb,
                                                   u16* __restrict__ wt) {
  const int tid = threadIdx.x;
  if (blockIdx.z == 4) {
    const int bid = blockIdx.y * 32 + blockIdx.x;
#pragma unroll
    for (int it = 0; it < 4; ++it) {
      const int i = bid * 1024 + it * 256 + tid;
      float4 v = ((const float4*)x)[i];
      ushort4 o;
      o.x = f2bf(v.x); o.y = f2bf(v.y); o.z = f2bf(v.z); o.w = f2bf(v.w);
      ((ushort4*)xb)[i] = o;
    }
    return;
  }
  const float* src = (blockIdx.z == 0) ? wq : (blockIdx.z == 1) ? wk
                   : (blockIdx.z == 2) ? wv : wo;
  u16* dst = wt + (size_t)blockIdx.z * (HID * HID);
  __shared__ float tile[32][33];
  const int n0 = blockIdx.x * 32, k0 = blockIdx.y * 32;
  const int xx = tid & 31, yy = tid >> 5;
  for (int i = yy; i < 32; i += 8)
    tile[i][xx] = src[(size_t)(k0 + i) * HID + n0 + xx];
  __syncthreads();
  for (int i = yy; i < 32; i += 8)
    dst[(size_t)(n0 + i) * HID + k0 + xx] = f2bf(tile[xx][i]);
}

// ------------- fused QKV GEMM, BK=64 -------------
// 128x128 tile, 16 K-iters (vs 32 at BK=32): half the barrier/async overhead.
// Staging xor-swizzled (16B chunks) -> conflict-free b128 LDS reads, no padding.
// Q,K row-major bf16; V transposed f16 to VT[b,h,d,s] via LDS epilogue.
__global__ __launch_bounds__(256) void gemm_qkv_kernel(const u16* __restrict__ A,
                                                       const u16* __restrict__ Bt,
                                                       const float* __restrict__ bq,
                                                       const float* __restrict__ bk,
                                                       const float* __restrict__ bv,
                                                       u16* __restrict__ Qb,
                                                       u16* __restrict__ Kb,
                                                       u16* __restrict__ VTf) {
  __shared__ u16 smem[16384];                // sA(16KB) | sB(16KB)
  u16* sA = smem;
  u16* sB = smem + 8192;
  const int tid  = threadIdx.x;
  const int wave = tid >> 6, lane = tid & 63;
  const int quad = lane >> 4, l16 = lane & 15;
  const int n0g = blockIdx.x * 128;
  const int region = blockIdx.x >> 3;        // 0=Q 1=K 2=V
  const int colbase = (blockIdx.x & 7) * 128;
  const int m0 = blockIdx.y * 128;
  const int wm = (wave & 1) * 64, wn = (wave >> 1) * 64;

  f32x4 acc[4][4] = {};
  // staging: chunk = 8 rows x 64 cols (1KB). lane -> row lane>>3, 16B col chunk
  const int sr8 = lane >> 3;                 // row within chunk
  const int gch = (lane & 7) ^ sr8;          // xor-swizzled global 16B chunk
  const int px  = quad ^ (l16 & 7);          // read-side phys chunk for slice 0

  for (int kt = 0; kt < HID; kt += 64) {
    __syncthreads();
    for (int c = wave; c < 16; c += 4) {
      async_ld16(A  + (size_t)(m0  + c * 8 + sr8) * HID + kt + gch * 8, &sA[c * 512]);
      async_ld16(Bt + (size_t)(n0g + c * 8 + sr8) * HID + kt + gch * 8, &sB[c * 512]);
    }
    __syncthreads();

    bf16x8 af[4], bfr[4];
#pragma unroll
    for (int t = 0; t < 4; ++t) {
      af[t]  = *(const bf16x8*)&sA[(wm + t * 16 + l16) * 64 + px * 8];
      bfr[t] = *(const bf16x8*)&sB[(wn + t * 16 + l16) * 64 + px * 8];
    }
#pragma unroll
    for (int mt = 0; mt < 4; ++mt)
#pragma unroll
      for (int nt = 0; nt < 4; ++nt)
        acc[mt][nt] = __builtin_amdgcn_mfma_f32_16x16x32_bf16(af[mt], bfr[nt],
                                                              acc[mt][nt], 0, 0, 0);
#pragma unroll
    for (int t = 0; t < 4; ++t) {
      af[t]  = *(const bf16x8*)&sA[(wm + t * 16 + l16) * 64 + (px ^ 4) * 8];
      bfr[t] = *(const bf16x8*)&sB[(wn + t * 16 + l16) * 64 + (px ^ 4) * 8];
    }
#pragma unroll
    for (int mt = 0; mt < 4; ++mt)
#pragma unroll
      for (int nt = 0; nt < 4; ++nt)
        acc[mt][nt] = __builtin_amdgcn_mfma_f32_16x16x32_bf16(af[mt], bfr[nt],
                                                              acc[mt][nt], 0, 0, 0);
  }

  const float* bias = (region == 0) ? bq : (region == 1) ? bk : bv;
  float bvv[4];
#pragma unroll
  for (int nt = 0; nt < 4; ++nt) bvv[nt] = bias[colbase + wn + nt * 16 + l16];

  if (region == 2) {
    // --- transposed f16 epilogue: VT[(b*16+h)*64+d][s], two 64-col halves ---
    const int bb = m0 >> 11;
    const int m0loc = m0 & 2047;
    const int h0 = colbase >> 6;
    u16* T = smem;                      // [64 d][128 s] u16, chunk-swizzled
#pragma unroll
    for (int h2 = 0; h2 < 2; ++h2) {
      __syncthreads();
      if ((wave >> 1) == h2) {
#pragma unroll
        for (int mt = 0; mt < 4; ++mt)
#pragma unroll
          for (int nt = 0; nt < 4; ++nt)
#pragma unroll
            for (int r = 0; r < 4; ++r) {
              const int sl = (wave & 1) * 64 + mt * 16 + quad * 4 + r;
              const int dl = nt * 16 + l16;
              union { f16 h; u16 u; } cv;
              cv.h = (f16)(acc[mt][nt][r] + bvv[nt]);
              T[dl * 128 + (((sl >> 3) ^ l16) * 8) + (sl & 7)] = cv.u;
            }
      }
      __syncthreads();
      const int d = tid >> 2, sg = (tid & 3) * 4;
      u16* drow = VTf + (size_t)((bb * NHEAD + h0 + h2) * HDIM + d) * SLEN + m0loc;
#pragma unroll
      for (int cc = 0; cc < 4; ++cc) {
        const int cl = sg + cc;
        const int ph = cl ^ (d & 15);
        *(bf16x8*)(drow + cl * 8) = *(const bf16x8*)&T[d * 128 + ph * 8];
      }
    }
    return;
  }

  u16* C = (region == 0) ? Qb : Kb;
#pragma unroll
  for (int mt = 0; mt < 4; ++mt)
#pragma unroll
    for (int r = 0; r < 4; ++r) {
      const int row = m0 + wm + mt * 16 + quad * 4 + r;
#pragma unroll
      for (int nt = 0; nt < 4; ++nt) {
        const int col = colbase + wn + nt * 16 + l16;
        C[(size_t)row * HID + col] = f2bf(acc[mt][nt][r] + bvv[nt]);
      }
    }
}

// ------------- O-proj GEMM, BK=64: out[4096][1024] = A @ Wt^T + b (fp32) -------------
__global__ __launch_bounds__(256) void gemm_o_kernel(const u16* __restrict__ A,
                                                     const u16* __restrict__ Bt,
                                                     const float* __restrict__ bias,
                                                     float* __restrict__ Cf) {
  __shared__ u16 smem[12288];                // sA 64x64(8KB) | sB 128x64(16KB)
  u16* sA = smem;
  u16* sB = smem + 4096;
  const int tid  = threadIdx.x;
  const int wave = tid >> 6, lane = tid & 63;
  const int quad = lane >> 4, l16 = lane & 15;
  const int n0 = blockIdx.x * 128;
  const int m0 = blockIdx.y * 64;
  const int wn = wave * 32;

  f32x4 acc[4][2] = {};
  const int sr8 = lane >> 3;
  const int gch = (lane & 7) ^ sr8;
  const int px  = quad ^ (l16 & 7);

  for (int kt = 0; kt < HID; kt += 64) {
    __syncthreads();
    for (int c = wave; c < 24; c += 4) {     // 0-7: A chunks, 8-23: B chunks
      if (c < 8) async_ld16(A  + (size_t)(m0 + c * 8 + sr8) * HID + kt + gch * 8,
                            &sA[c * 512]);
      else       async_ld16(Bt + (size_t)(n0 + (c - 8) * 8 + sr8) * HID + kt + gch * 8,
                            &sB[(c - 8) * 512]);
    }
    __syncthreads();

    bf16x8 af[4], bfr[2];
#pragma unroll
    for (int t = 0; t < 4; ++t)
      af[t] = *(const bf16x8*)&sA[(t * 16 + l16) * 64 + px * 8];
#pragma unroll
    for (int t = 0; t < 2; ++t)
      bfr[t] = *(const bf16x8*)&sB[(wn + t * 16 + l16) * 64 + px * 8];
#pragma unroll
    for (int mt = 0; mt < 4; ++mt)
#pragma unroll
      for (int nt = 0; nt < 2; ++nt)
        acc[mt][nt] = __builtin_amdgcn_mfma_f32_16x16x32_bf16(af[mt], bfr[nt],
                                                              acc[mt][nt], 0, 0, 0);
#pragma unroll
    for (int t = 0; t < 4; ++t)
      af[t] = *(const bf16x8*)&sA[(t * 16 + l16) * 64 + (px ^ 4) * 8];
#pragma unroll
    for (int t = 0; t < 2; ++t)
      bfr[t] = *(const bf16x8*)&sB[(wn + t * 16 + l16) * 64 + (px ^ 4) * 8];
#pragma unroll
    for (int mt = 0; mt < 4; ++mt)
#pragma unroll
      for (int nt = 0; nt < 2; ++nt)
        acc[mt][nt] = __builtin_amdgcn_mfma_f32_16x16x32_bf16(af[mt], bfr[nt],
                                                              acc[mt][nt], 0, 0, 0);
  }

  float bvv[2];
#pragma unroll
  for (int nt = 0; nt < 2; ++nt) bvv[nt] = bias[n0 + wn + nt * 16 + l16];
#pragma unroll
  for (int mt = 0; mt < 4; ++mt)
#pragma unroll
    for (int r = 0; r < 4; ++r) {
      const int row = m0 + mt * 16 + quad * 4 + r;
#pragma unroll
      for (int nt = 0; nt < 2; ++nt)
        Cf[(size_t)row * HID + n0 + wn + nt * 16 + l16] = acc[mt][nt][r] + bvv[nt];
    }
}

// ---------------- causal flash attention (R5 version, best measured 56.2us) ----------------
__global__ __launch_bounds__(256, 2) void flash_attn_kernel(const u16* __restrict__ Q,
                                                            const u16* __restrict__ K,
                                                            const u16* __restrict__ VT,
                                                            const int* __restrict__ mask,
                                                            u16* __restrict__ O) {
  const int xb = blockIdx.x, h = blockIdx.y, b = blockIdx.z;
  const int tid  = threadIdx.x;
  const int wave = tid >> 6, lane = tid & 63;
  const int quad = lane >> 4, l16 = lane & 15;

  __shared__ alignas(16) char smraw[35840];
  u16*   Ks  = (u16*)smraw;                  // [2][64*64] bf16, swizzled chunks
  u16*   Vt  = (u16*)(smraw + 16384);        // [2][64*64] f16,  swizzled chunks
  float* Ob0 = (float*)smraw;                // [64][66] f32 (epilogue alias)
  float* Ob1 = (float*)(smraw + 16896);
  float* lb  = (float*)(smraw + 33792);      // [4][64]

  const u16* Kh  = K  + (size_t)b * SLEN * HID + h * HDIM;
  const u16* Vth = VT + (size_t)((b * NHEAD + h) * HDIM) * SLEN;

  const int srow8 = lane >> 3;
  const int gch   = (lane & 7) ^ srow8;
  const int rx    = l16 & 7;

  for (int phase = 0; phase < 2; ++phase) {
    const int qt = phase ? (31 - xb) : xb;
    const int q0 = qt * 64;

    bf16x8 qb[4][2];
#pragma unroll
    for (int nt = 0; nt < 4; ++nt) {
      const u16* qp = Q + (size_t)(b * SLEN + q0 + nt * 16 + l16) * HID + h * HDIM + quad * 8;
      qb[nt][0] = *(const bf16x8*)qp;
      qb[nt][1] = *(const bf16x8*)(qp + 32);
    }

    f32x4 oacc[4][4] = {};
    float l_part[4] = {0.f, 0.f, 0.f, 0.f};

    {
      const int r0 = wave * 16 + srow8;
      async_ld16(Kh  + (size_t)r0 * HID + gch * 8,        Ks + wave * 1024);
      async_ld16(Kh  + (size_t)(r0 + 8) * HID + gch * 8,  Ks + wave * 1024 + 512);
      async_ld16(Vth + (size_t)r0 * SLEN + gch * 8,       Vt + wave * 1024);
      async_ld16(Vth + (size_t)(r0 + 8) * SLEN + gch * 8, Vt + wave * 1024 + 512);
    }
    __syncthreads();

    for (int j = 0; j <= qt; ++j) {
      const int buf = j & 1;
      u16* KsB = Ks + buf * 4096;
      u16* VtB = Vt + buf * 4096;

      if (j < qt) {
        const int nb = (buf ^ 1) * 4096;
        const int jn = (j + 1) * 64;
        const int r0 = wave * 16 + srow8;
        async_ld16(Kh  + (size_t)(jn + r0) * HID + gch * 8,       Ks + nb + wave * 1024);
        async_ld16(Kh  + (size_t)(jn + r0 + 8) * HID + gch * 8,   Ks + nb + wave * 1024 + 512);
        async_ld16(Vth + (size_t)r0 * SLEN + jn + gch * 8,        Vt + nb + wave * 1024);
        async_ld16(Vth + (size_t)(r0 + 8) * SLEN + jn + gch * 8,  Vt + nb + wave * 1024 + 512);
      }

      const int4 mi = *(const int4*)(mask + b * SLEN + j * 64 + wave * 16 + quad * 4);
      float map[4];
      map[0] = mi.x ? 0.f : -1e30f;  map[1] = mi.y ? 0.f : -1e30f;
      map[2] = mi.z ? 0.f : -1e30f;  map[3] = mi.w ? 0.f : -1e30f;

      const u16* kp = KsB + (wave * 16 + l16) * 64;
      const int ph0 = quad ^ rx;
      const bf16x8 ka0 = *(const bf16x8*)(kp + ph0 * 8);
      const bf16x8 ka1 = *(const bf16x8*)(kp + (ph0 ^ 4) * 8);

      float p[4][4];
#pragma unroll
      for (int nt = 0; nt < 4; ++nt) {
        f32x4 z = {0.f, 0.f, 0.f, 0.f};
        z = __builtin_amdgcn_mfma_f32_16x16x32_bf16(ka0, qb[nt][0], z, 0, 0, 0);
        z = __builtin_amdgcn_mfma_f32_16x16x32_bf16(ka1, qb[nt][1], z, 0, 0, 0);
#pragma unroll
        for (int r = 0; r < 4; ++r)
          p[nt][r] = exp2f(fmaf(z[r], SC2L, map[r]));
      }
      if (j == qt) {
#pragma unroll
        for (int nt = 0; nt < 4; ++nt)
#pragma unroll
          for (int r = 0; r < 4; ++r)
            if (wave * 16 + quad * 4 + r > nt * 16 + l16) p[nt][r] = 0.f;
      }

      f16x4 pb[4];
#pragma unroll
      for (int nt = 0; nt < 4; ++nt) {
        l_part[nt] += (p[nt][0] + p[nt][1]) + (p[nt][2] + p[nt][3]);
        const h16x2 lo = __builtin_amdgcn_cvt_pkrtz(p[nt][0], p[nt][1]);
        const h16x2 hi = __builtin_amdgcn_cvt_pkrtz(p[nt][2], p[nt][3]);
        const h16x4 packed = __builtin_shufflevector(lo, hi, 0, 1, 2, 3);
        pb[nt] = __builtin_bit_cast(f16x4, packed);
      }

      const int phv = (wave * 2 + (quad >> 1)) ^ rx;
      const int vsub = phv * 8 + (quad & 1) * 4;
#pragma unroll
      for (int dt = 0; dt < 4; ++dt) {
        const f16x4 va = *(const f16x4*)(VtB + (dt * 16 + l16) * 64 + vsub);
#pragma unroll
        for (int nt = 0; nt < 4; ++nt)
          oacc[dt][nt] = __builtin_amdgcn_mfma_f32_16x16x16f16(va, pb[nt], oacc[dt][nt], 0, 0, 0);
      }
      __syncthreads();
    }

#pragma unroll
    for (int nt = 0; nt < 4; ++nt) {
      l_part[nt] += __shfl_xor(l_part[nt], 16);
      l_part[nt] += __shfl_xor(l_part[nt], 32);
    }
    if (quad == 0)
#pragma unroll
      for (int nt = 0; nt < 4; ++nt) lb[wave * 64 + nt * 16 + l16] = l_part[nt];

    if ((wave & 1) == 0) {
      float* ob = (wave == 0) ? Ob0 : Ob1;
#pragma unroll
      for (int dt = 0; dt < 4; ++dt)
#pragma unroll
        for (int nt = 0; nt < 4; ++nt)
#pragma unroll
          for (int r = 0; r < 4; ++r)
            ob[(dt * 16 + quad * 4 + r) * 66 + nt * 16 + l16] = oacc[dt][nt][r];
    }
    __syncthreads();
    if (wave & 1) {
      float* ob = (wave == 1) ? Ob0 : Ob1;
#pragma unroll
      for (int dt = 0; dt < 4; ++dt)
#pragma unroll
        for (int nt = 0; nt < 4; ++nt)
#pragma unroll
          for (int r = 0; r < 4; ++r)
            ob[(dt * 16 + quad * 4 + r) * 66 + nt * 16 + l16] += oacc[dt][nt][r];
    }
    __syncthreads();

    {
      const int q  = tid >> 2;
      const int dc = tid & 3;
      const float l = lb[q] + lb[64 + q] + lb[128 + q] + lb[192 + q];
      const float inv = 1.f / l;
      u16 ob[16];
#pragma unroll
      for (int e = 0; e < 16; ++e) {
        const int d = dc * 16 + e;
        ob[e] = f2bf((Ob0[d * 66 + q] + Ob1[d * 66 + q]) * inv);
      }
      u16* op = O + (size_t)(b * SLEN + q0 + q) * HID + h * HDIM + dc * 16;
      *(bf16x8*)op       = *(bf16x8*)&ob[0];
      *(bf16x8*)(op + 8) = *(bf16x8*)&ob[8];
    }
    __syncthreads();
  }
}

// ---------------- launcher ----------------
extern "C" void kernel_launch(void* const* d_in, const int* in_sizes, int n_in,
                              void* d_out, int out_size, void* d_ws, size_t ws_size,
                              hipStream_t stream) {
  const float* x    = (const float*)d_in[0];
  const int*   mask = (const int*)d_in[1];
  const float* wq   = (const float*)d_in[2];
  const float* bq   = (const float*)d_in[3];
  const float* wk   = (const float*)d_in[4];
  const float* bk   = (const float*)d_in[5];
  const float* wv   = (const float*)d_in[6];
  const float* bv   = (const float*)d_in[7];
  const float* wo   = (const float*)d_in[8];
  const float* bo   = (const float*)d_in[9];
  float* out = (float*)d_out;

  char* ws = (char*)d_ws;
  u16* XBF = (u16*)(ws);                      // 8 MB (dead after QKV GEMM)
  u16* WT  = (u16*)(ws + (8u  << 20));        // 4x2 MB transposed bf16 weights
  u16* QBF = (u16*)(ws + (16u << 20));        // 8 MB
  u16* KBF = (u16*)(ws + (24u << 20));        // 8 MB
  u16* VTF = (u16*)(ws + (32u << 20));        // 8 MB f16 V^T [b,h,d,s]
  u16* ATT = (u16*)(ws);                      // 8 MB, reuses XBF slot

  prep_kernel<<<dim3(32, 32, 5), 256, 0, stream>>>(x, wq, wk, wv, wo, XBF, WT);
  gemm_qkv_kernel<<<dim3(24, 32), 256, 0, stream>>>(XBF, WT, bq, bk, bv, QBF, KBF, VTF);
  flash_attn_kernel<<<dim3(16, NHEAD, 2), 256, 0, stream>>>(QBF, KBF, VTF, mask, ATT);
  gemm_o_kernel<<<dim3(8, 64), 256, 0, stream>>>(ATT, WT + (3u << 20), bo, out);
}